// Round 6
// baseline (1686.926 us; speedup 1.0000x reference)
//
#include <hip/hip_runtime.h>

// ---------------------------------------------------------------------------
// TypeNet: 3 branches x (BN1 -> flattened LSTM (2048 steps) -> BN2 -> LSTM (2048 steps))
// H = 128, gates = 512. Round 18 (resubmit x3; R3/R4/R5 benches all
// GPUAcquisitionTimeout): replace the i8 MFMA recurrence with v_dot4_i32_i8.
// The recurrence is a mat-vec; MFMA's 16x16 output tile uses only 1/16
// columns (~50 useful MAC/cyc/SIMD). dot4 on the VALU does 128 useful
// MAC/cyc/SIMD. New mapping: 1 thread = 1 gate-row; 32 packed i8 weight
// dwords in VGPRs; h broadcast via 8x ds_read_b128 (uniform addr). Integer
// accumulation identical to MFMA -> numerics unchanged vs R16/R17 (exact
// f32 step-0 preact, noise-shaped h quant, pre-scaled Gx). Deleted: afrag
// packing, acc-select tree, rowscale LDS, setprio (neutral in R17 A/B).
// ---------------------------------------------------------------------------

typedef _Float16 half4_t __attribute__((ext_vector_type(4)));
typedef _Float16 half8 __attribute__((ext_vector_type(8)));
typedef float float4_t __attribute__((ext_vector_type(4)));
typedef int int4_t __attribute__((ext_vector_type(4)));

#define LOG2E 1.44269504f

__device__ __forceinline__ float fast_rcp(float x) { return __builtin_amdgcn_rcpf(x); }
__device__ __forceinline__ float exp2b(float x) { return __builtin_amdgcn_exp2f(x); }

// signed i8x4 dot product with i32 accumulate (v_dot4_i32_i8)
__device__ __forceinline__ int dot4i8(int a, int b, int c) {
#if __has_builtin(__builtin_amdgcn_sdot4)
  return __builtin_amdgcn_sdot4(a, b, c, false);
#else
  int d;
  asm("v_dot4_i32_i8 %0, %1, %2, %3" : "=v"(d) : "v"(a), "v"(b), "v"(c));
  return d;
#endif
}

// DPP quad broadcast: lane PAT of each aligned 4-lane group to all 4.
#define QBCAST(x, pat)                                                        \
  __int_as_float(__builtin_amdgcn_update_dpp(0, __float_as_int(x), (pat),     \
                                             0xF, 0xF, true))

// LDS-visibility-only barrier: no vmcnt drain (global stores/loads in flight).
__device__ __forceinline__ void lds_barrier() {
  asm volatile("s_waitcnt lgkmcnt(0)\n\ts_barrier" ::: "memory");
}

// Gx record index for (j, gate): ridx = (j>>4)*64 + ((j>>2)&3)*16 + (j&3)*4 + gate
__host__ __device__ __forceinline__ int ridx0_of(int j) {
  return (j >> 4) * 64 + ((j >> 2) & 3) * 16 + (j & 3) * 4;
}

// ---------------------------------------------------------------------------
// K1: BN1 over branch slice [128,16,3]; writes xbn[br][s=t*128+b][d].
// ---------------------------------------------------------------------------
__global__ __launch_bounds__(128) void bn1_kernel(const float* __restrict__ x,
                                                  const float* __restrict__ g1,
                                                  const float* __restrict__ b1,
                                                  float* __restrict__ xbn) {
  const int br = blockIdx.x >> 4;
  const int t  = blockIdx.x & 15;
  const int b  = threadIdx.x;
  const float* px = x + (b * 48 + br * 16 + t) * 3;
  const float v0 = px[0], v1 = px[1], v2 = px[2];
  float s  = v0 + v1 + v2;
  float ss = v0 * v0 + v1 * v1 + v2 * v2;
  for (int off = 32; off; off >>= 1) {
    s  += __shfl_down(s, off);
    ss += __shfl_down(ss, off);
  }
  __shared__ float red[4];
  if ((threadIdx.x & 63) == 0) {
    red[(threadIdx.x >> 6) * 2]     = s;
    red[(threadIdx.x >> 6) * 2 + 1] = ss;
  }
  __syncthreads();
  const float S = red[0] + red[2], SS = red[1] + red[3];
  const float mean = S * (1.0f / 384.0f);
  const float var  = SS * (1.0f / 384.0f) - mean * mean;
  const float rstd = rsqrtf(var + 1e-5f);
  const float a  = g1[t] * rstd;
  const float sh = b1[t] - mean * a;
  float* dst = xbn + br * 6144 + (t * 128 + b) * 3;
  dst[0] = v0 * a + sh;
  dst[1] = v1 * a + sh;
  dst[2] = v2 * a + sh;
}

// ---------------------------------------------------------------------------
// K1b: G1x = (Wih1 @ xbn + bih1 + bhh1) * log2e, chunked layout w/ ridx map.
// Gate 2 (tanh) pre-doubled: folds the s=2 activation scale out of the
// recurrence's critical path.
// ---------------------------------------------------------------------------
__global__ __launch_bounds__(256) void g1x_kernel(const float* __restrict__ xbn,
                                                  const float* __restrict__ Wih1,
                                                  const float* __restrict__ bih1,
                                                  const float* __restrict__ bhh1,
                                                  _Float16* __restrict__ G1x) {
  const int br = blockIdx.x >> 10;
  const int sp = blockIdx.x & 1023;
  const int s  = sp * 2 + (threadIdx.x >> 7);
  const int j  = threadIdx.x & 127;
  const float* px = xbn + br * 6144 + s * 3;
  const float x0 = px[0], x1 = px[1], x2 = px[2];
  _Float16* base =
      G1x + ((size_t)(br * 128 + (s >> 4)) * 512 + ridx0_of(j)) * 16 + (s & 15);
#pragma unroll
  for (int g = 0; g < 4; ++g) {
    const int row = g * 128 + j;
    float a = bih1[row] + bhh1[row] + Wih1[row * 3] * x0 +
              Wih1[row * 3 + 1] * x1 + Wih1[row * 3 + 2] * x2;
    a *= (g == 2) ? (2.0f * LOG2E) : LOG2E;
    base[g * 16] = (_Float16)a;
  }
}

// ---------------------------------------------------------------------------
// K3a: BN2 stats per (branch, channel) over 2048 elems of H1.
// ---------------------------------------------------------------------------
__global__ __launch_bounds__(256) void bn2stats_kernel(const float* __restrict__ H1,
                                                       float* __restrict__ stats) {
  const int br = blockIdx.x >> 7;
  const int ch = blockIdx.x & 127;
  const float* base = H1 + (size_t)br * 262144 + ch * 128;
  float s = 0.f, ss = 0.f;
  for (int k = threadIdx.x; k < 2048; k += 256) {
    const int t1 = k >> 7, h = k & 127;
    const float v = base[t1 * 16384 + h];
    s += v;
    ss += v * v;
  }
  for (int off = 32; off; off >>= 1) {
    s  += __shfl_down(s, off);
    ss += __shfl_down(ss, off);
  }
  __shared__ float red[8];
  if ((threadIdx.x & 63) == 0) {
    red[(threadIdx.x >> 6) * 2]     = s;
    red[(threadIdx.x >> 6) * 2 + 1] = ss;
  }
  __syncthreads();
  if (threadIdx.x == 0) {
    const float S  = red[0] + red[2] + red[4] + red[6];
    const float SS = red[1] + red[3] + red[5] + red[7];
    const float mean = S * (1.0f / 2048.0f);
    const float var  = SS * (1.0f / 2048.0f) - mean * mean;
    stats[(br * 128 + ch) * 2]     = mean;
    stats[(br * 128 + ch) * 2 + 1] = rsqrtf(var + 1e-5f);
  }
}

// ---------------------------------------------------------------------------
// K3b: G2x = (Wih2 @ BN2(H1) + biases) * log2e, chunked layout w/ ridx map.
// Gate 2 pre-doubled (see g1x).
// ---------------------------------------------------------------------------
__global__ __launch_bounds__(256) void g2x_kernel(
    const float* __restrict__ H1, const float* __restrict__ stats,
    const float* __restrict__ g2, const float* __restrict__ b2v,
    const float* __restrict__ Wih2, const float* __restrict__ bih2,
    const float* __restrict__ bhh2, _Float16* __restrict__ G2x) {
  const int br = blockIdx.x >> 7;
  const int t2 = blockIdx.x & 127;
  __shared__ float xh[2048];
  __shared__ float wt[64 * 129];
  const float mean = stats[(br * 128 + t2) * 2];
  const float rstd = stats[(br * 128 + t2) * 2 + 1];
  const float a  = g2[t2] * rstd;
  const float sh = b2v[t2] - mean * a;
  for (int e = threadIdx.x; e < 2048; e += 256) {
    const int b2 = e >> 7, d = e & 127;
    xh[e] = H1[(size_t)br * 262144 + (size_t)(b2 * 128 + t2) * 128 + d] * a + sh;
  }
  const int gl  = threadIdx.x & 63;
  const int b2b = (threadIdx.x >> 6) * 4;
  for (int gt = 0; gt < 8; ++gt) {
    __syncthreads();
    for (int e = threadIdx.x; e < 8192; e += 256)
      wt[(e >> 7) * 129 + (e & 127)] = Wih2[gt * 8192 + e];
    __syncthreads();
    float a0 = 0.f, a1 = 0.f, a2 = 0.f, a3 = 0.f;
    for (int d = 0; d < 128; ++d) {
      const float w = wt[gl * 129 + d];
      a0 += w * xh[(b2b + 0) * 128 + d];
      a1 += w * xh[(b2b + 1) * 128 + d];
      a2 += w * xh[(b2b + 2) * 128 + d];
      a3 += w * xh[(b2b + 3) * 128 + d];
    }
    const int g    = gt * 64 + gl;
    const int gate = g >> 7;
    const int jj   = g & 127;
    const int ri   = ridx0_of(jj) + gate;
    const float bb = bih2[g] + bhh2[g];
    const float mul = (gate == 2) ? (2.0f * LOG2E) : LOG2E;
    _Float16* dst = G2x + ((size_t)(br * 128 + t2) * 512 + ri) * 16 + b2b;
    *reinterpret_cast<half4_t*>(dst) =
        half4_t{(_Float16)((a0 + bb) * mul), (_Float16)((a1 + bb) * mul),
                (_Float16)((a2 + bb) * mul), (_Float16)((a3 + bb) * mul)};
  }
}

// ---------------------------------------------------------------------------
// K2/K4: the recurrence. 1 block/branch, 512 threads (8 waves, 2/SIMD).
// 1 thread = 1 gate-row (row = gate*128 + j). Own row's i8 weights packed
// in 32 VGPRs; per step: 8x ds_read_b128 broadcast of h (128 i8) + 32x
// v_dot4_i32_i8 (4 chains of 8) -> i32 preact, then the same epilogue as
// R16/R17 (unified activation, QBCAST gate collect, noise-shaped h quant,
// exact f32 step 0). One lgkm-only barrier per step.
// ---------------------------------------------------------------------------
__global__ __launch_bounds__(512, 1) void lstm_kernel(
    const float* __restrict__ Whh, const float* __restrict__ h0s,
    const float* __restrict__ c0s, const _Float16* __restrict__ Gx,
    float* __restrict__ outp, int layer) {
  const int br   = blockIdx.x;
  const int tid  = threadIdx.x;
  const int wave = tid >> 6;
  const int lane = tid & 63;
  const int quad = lane >> 4;
  const int l15  = lane & 15;
  const int gate = l15 & 3;
  const int rr   = l15 >> 2;
  const int j    = wave * 16 + quad * 4 + rr;  // this lane's cell row
  const int row  = gate * 128 + j;             // this lane's gate row
  // unified activation: sigm (i,f,o): B=1; tanh (g): B=2. The input scale
  // (s=2 for tanh) is pre-folded into Gx (producer) and s_own/exact0 below.
  const float scg = (gate == 2) ? 2.0f : 1.0f;
  const float Bcg = (gate == 2) ? 2.0f : 1.0f;

  __shared__ __align__(16) signed char h_sh[2][128];
  __shared__ __align__(16) float h0f[128];

  // ---- quantize OWN row of Whh to i8 (per-row absmax scale), 32 dwords ----
  const float4_t* wr = (const float4_t*)(Whh + row * 128);
  float m = 1e-8f;
  for (int k4 = 0; k4 < 32; ++k4) {
    const float4_t v = wr[k4];
    m = fmaxf(m, fmaxf(fmaxf(fabsf(v[0]), fabsf(v[1])),
                       fmaxf(fabsf(v[2]), fabsf(v[3]))));
  }
  const float inv = 127.0f / m;
  int wq[32];
#pragma unroll
  for (int d = 0; d < 32; ++d) {
    const float4_t v = wr[d];
    int word = 0;
#pragma unroll
    for (int b = 0; b < 4; ++b) {
      const int q = (int)__builtin_rintf(v[b] * inv);
      word |= (q & 255) << (8 * b);
    }
    wq[d] = word;
  }
  // dequant scale for own row (log2e + tanh-scale folded)
  const float s_own = m * (LOG2E / (127.0f * 127.0f)) * scg;

  const int slot = 2 * br + layer;
  float c = c0s[slot * 128 + j];  // 4 gate-lanes per j hold identical c
  if (tid < 128) {
    const float h0 = h0s[slot * 128 + tid];
    h0f[tid] = h0;
    // i8 encoding of h0 is irrelevant (step-0 result is overridden); clip.
    float qf = __builtin_rintf(h0 * 127.0f);
    qf = fminf(fmaxf(qf, -127.0f), 127.0f);
    h_sh[0][tid] = (signed char)(int)qf;
  }

  // Gx chunk stream: record = 16 halfs at ((br*128+ch)*512 + tid)*16
  const half8* gq = (const half8*)Gx;
  half8 curA = gq[((size_t)(br * 128) * 512 + tid) * 2];
  half8 curB = gq[((size_t)(br * 128) * 512 + tid) * 2 + 1];
  float* const obase = outp + (size_t)br * 262144;

  __syncthreads();  // publishes h0f + h_sh[0]

  // ---- EXACT f32 step-0 preact for the owned cell (one-time) ----
  float exact0;
  {
    const float4_t* h04 = (const float4_t*)h0f;
    float e0 = 0.f, e1 = 0.f;
#pragma unroll 8
    for (int k4 = 0; k4 < 32; k4 += 2) {
      const float4_t a0 = wr[k4],     b0 = h04[k4];
      const float4_t a1 = wr[k4 + 1], b1 = h04[k4 + 1];
      e0 = __builtin_fmaf(a0[0], b0[0], e0);
      e0 = __builtin_fmaf(a0[1], b0[1], e0);
      e0 = __builtin_fmaf(a0[2], b0[2], e0);
      e0 = __builtin_fmaf(a0[3], b0[3], e0);
      e1 = __builtin_fmaf(a1[0], b1[0], e1);
      e1 = __builtin_fmaf(a1[1], b1[1], e1);
      e1 = __builtin_fmaf(a1[2], b1[2], e1);
      e1 = __builtin_fmaf(a1[3], b1[3], e1);
    }
    exact0 = (e0 + e1) * (LOG2E * scg);
  }

  float qres = 0.f;  // noise-shaping residual, kept in 127-scale

  for (int chk = 0; chk < 128; ++chk) {
    const int chn = (chk < 127) ? chk + 1 : 127;
    const size_t nrec = ((size_t)(br * 128 + chn) * 512 + tid) * 2;
    const half8 nA = gq[nrec], nB = gq[nrec + 1];  // waited at chunk end

#pragma unroll
    for (int u = 0; u < 16; ++u) {
      // h broadcast: 8x ds_read_b128, uniform address across the wave
      const int4_t* hv4 = (const int4_t*)h_sh[u & 1];
      int hdw[32];
#pragma unroll
      for (int r = 0; r < 8; ++r) {
        const int4_t hh = hv4[r];
        hdw[r * 4 + 0] = hh[0];
        hdw[r * 4 + 1] = hh[1];
        hdw[r * 4 + 2] = hh[2];
        hdw[r * 4 + 3] = hh[3];
      }

      const float pre = (float)((u < 8) ? curA[u] : curB[u - 8]);

      // own-row dot product: 32 sdot4 in 4 independent chains of 8
      int a0 = 0, a1 = 0, a2 = 0, a3 = 0;
#pragma unroll
      for (int i = 0; i < 8; ++i) {
        a0 = dot4i8(wq[i],      hdw[i],      a0);
        a1 = dot4i8(wq[8 + i],  hdw[8 + i],  a1);
        a2 = dot4i8(wq[16 + i], hdw[16 + i], a2);
        a3 = dot4i8(wq[24 + i], hdw[24 + i], a3);
      }
      const int ei = (a0 + a1) + (a2 + a3);

      float a = __builtin_fmaf((float)ei, s_own, pre);
      if (u == 0 && chk == 0) a = exact0 + pre;  // exact step 0 (no h0 quant)

      // unified activation: 1 - B*rcp(1 + exp2(a))  (input scale pre-folded)
      const float act = __builtin_fmaf(-Bcg, fast_rcp(1.0f + exp2b(a)), 1.0f);

      // collect the 4 gates across the aligned 4-lane group
      const float iv = QBCAST(act, 0x00);
      const float fv = QBCAST(act, 0x55);
      const float gv = QBCAST(act, 0xAA);
      const float ov = QBCAST(act, 0xFF);

      c = fv * c + iv * gv;
      const float t  = __builtin_fmaf(
          -2.0f, fast_rcp(1.0f + exp2b(c * 2.88539008f)), 1.0f);
      const float hv = ov * t;

      if (gate == 0) {
        // noise-shaped quantization, residual kept 127-scaled:
        //   t2 = 127*hv + qres; qf = clamp(rint(t2)); qres' = t2 - qf
        const float t2 = __builtin_fmaf(hv, 127.0f, qres);
        float qf = __builtin_rintf(t2);
        qf = __builtin_amdgcn_fmed3f(qf, -127.0f, 127.0f);
        qres = t2 - qf;
        h_sh[(u + 1) & 1][j] = (signed char)(int)qf;
        // uniform row pointer: step advance is scalar (saddr form)
        float* orow = obase + (size_t)(chk * 16 + u) * 128;
        orow[j] = hv;  // output keeps full precision
      }
      lds_barrier();  // h broadcast; lgkm-only
    }

    curA = nA;  // vmcnt wait lands here, one full chunk after issue
    curB = nB;
  }
}

// ---------------------------------------------------------------------------
// Workspace layout (floats):
//   xbn   [3][2048][3]            @ 0        (18432)
//   H1    [3][2048][128]          @ 18432    (786432)
//   stats [3][128][2]             @ 804864   (768)
//   G1x   chunked f16             @ 805632   (1572864 floats)
//   G2x   chunked f16             @ 2378496  (1572864 floats)   total ~15.8 MB
// ---------------------------------------------------------------------------
extern "C" void kernel_launch(void* const* d_in, const int* in_sizes, int n_in,
                              void* d_out, int out_size, void* d_ws, size_t ws_size,
                              hipStream_t stream) {
  const float* x    = (const float*)d_in[0];
  const float* g1   = (const float*)d_in[1];
  const float* b1   = (const float*)d_in[2];
  const float* Wih1 = (const float*)d_in[3];
  const float* Whh1 = (const float*)d_in[4];
  const float* bih1 = (const float*)d_in[5];
  const float* bhh1 = (const float*)d_in[6];
  const float* g2   = (const float*)d_in[7];
  const float* b2   = (const float*)d_in[8];
  const float* Wih2 = (const float*)d_in[9];
  const float* Whh2 = (const float*)d_in[10];
  const float* bih2 = (const float*)d_in[11];
  const float* bhh2 = (const float*)d_in[12];
  const float* h0s  = (const float*)d_in[13];
  const float* c0s  = (const float*)d_in[14];

  float* ws   = (float*)d_ws;
  float* xbn  = ws;
  float* H1b  = ws + 18432;
  float* st   = ws + 18432 + 786432;
  _Float16* G1xb = (_Float16*)(ws + 805632);
  _Float16* G2xb = (_Float16*)(ws + 2378496);
  float* outp = (float*)d_out;

  bn1_kernel<<<48, 128, 0, stream>>>(x, g1, b1, xbn);
  g1x_kernel<<<3072, 256, 0, stream>>>(xbn, Wih1, bih1, bhh1, G1xb);
  lstm_kernel<<<3, 512, 0, stream>>>(Whh1, h0s, c0s, G1xb, H1b, 0);
  bn2stats_kernel<<<384, 256, 0, stream>>>(H1b, st);
  g2x_kernel<<<384, 256, 0, stream>>>(H1b, st, g2, b2, Wih2, bih2, bhh2, G2xb);
  lstm_kernel<<<3, 512, 0, stream>>>(Whh2, h0s, c0s, G2xb, outp, 1);
}

// Round 10
// 1509.427 us; speedup vs baseline: 1.1176x; 1.1176x over previous
//
#include <hip/hip_runtime.h>

// ---------------------------------------------------------------------------
// TypeNet: 3 branches x (BN1 -> flattened LSTM (2048 steps) -> BN2 -> LSTM (2048 steps))
// H = 128, gates = 512. Round 20 (resubmit x2; R8/R9 benches were
// GPUAcquisitionTimeout) = R17 (verified 1515.5 us, 682 us/lstm) + tanh
// exp2-factorization: keep cell state pre-scaled cp = 2*log2e*c; g-gate lane
// broadcasts 2.885*g via folded activation constants (B=5.7708, C=2.8854 ->
// zero extra ops); epilogue computes m1=fv*cp, m2=iv*gv' then
// exp2(m1)*exp2(m2) with both trans ops in parallel -- cuts ~2 dependent
// VALU ops off the serial chain per step. Everything else identical to R17
// (i8 MFMA recurrence: MFMA pipe proven hidden by R18's dot4 regression;
// exact f32 step-0 preact; noise-shaped h quant; 1 lgkm barrier/step).
// ---------------------------------------------------------------------------

typedef _Float16 half4_t __attribute__((ext_vector_type(4)));
typedef _Float16 half8 __attribute__((ext_vector_type(8)));
typedef float float4_t __attribute__((ext_vector_type(4)));
typedef int int4_t __attribute__((ext_vector_type(4)));

#define LOG2E 1.44269504f

__device__ __forceinline__ float fast_rcp(float x) { return __builtin_amdgcn_rcpf(x); }
__device__ __forceinline__ float exp2b(float x) { return __builtin_amdgcn_exp2f(x); }

// DPP quad broadcast: lane PAT of each aligned 4-lane group to all 4.
#define QBCAST(x, pat)                                                        \
  __int_as_float(__builtin_amdgcn_update_dpp(0, __float_as_int(x), (pat),     \
                                             0xF, 0xF, true))

// LDS-visibility-only barrier: no vmcnt drain (global stores/loads in flight).
__device__ __forceinline__ void lds_barrier() {
  asm volatile("s_waitcnt lgkmcnt(0)\n\ts_barrier" ::: "memory");
}

// Gx record index for (j, gate): ridx = (j>>4)*64 + ((j>>2)&3)*16 + (j&3)*4 + gate
__host__ __device__ __forceinline__ int ridx0_of(int j) {
  return (j >> 4) * 64 + ((j >> 2) & 3) * 16 + (j & 3) * 4;
}

// ---------------------------------------------------------------------------
// K1: BN1 over branch slice [128,16,3]; writes xbn[br][s=t*128+b][d].
// ---------------------------------------------------------------------------
__global__ __launch_bounds__(128) void bn1_kernel(const float* __restrict__ x,
                                                  const float* __restrict__ g1,
                                                  const float* __restrict__ b1,
                                                  float* __restrict__ xbn) {
  const int br = blockIdx.x >> 4;
  const int t  = blockIdx.x & 15;
  const int b  = threadIdx.x;
  const float* px = x + (b * 48 + br * 16 + t) * 3;
  const float v0 = px[0], v1 = px[1], v2 = px[2];
  float s  = v0 + v1 + v2;
  float ss = v0 * v0 + v1 * v1 + v2 * v2;
  for (int off = 32; off; off >>= 1) {
    s  += __shfl_down(s, off);
    ss += __shfl_down(ss, off);
  }
  __shared__ float red[4];
  if ((threadIdx.x & 63) == 0) {
    red[(threadIdx.x >> 6) * 2]     = s;
    red[(threadIdx.x >> 6) * 2 + 1] = ss;
  }
  __syncthreads();
  const float S = red[0] + red[2], SS = red[1] + red[3];
  const float mean = S * (1.0f / 384.0f);
  const float var  = SS * (1.0f / 384.0f) - mean * mean;
  const float rstd = rsqrtf(var + 1e-5f);
  const float a  = g1[t] * rstd;
  const float sh = b1[t] - mean * a;
  float* dst = xbn + br * 6144 + (t * 128 + b) * 3;
  dst[0] = v0 * a + sh;
  dst[1] = v1 * a + sh;
  dst[2] = v2 * a + sh;
}

// ---------------------------------------------------------------------------
// K1b: G1x = (Wih1 @ xbn + bih1 + bhh1) * log2e, chunked layout w/ ridx map.
// Gate 2 (tanh) pre-doubled: folds the s=2 activation scale out of the
// recurrence's critical path.
// ---------------------------------------------------------------------------
__global__ __launch_bounds__(256) void g1x_kernel(const float* __restrict__ xbn,
                                                  const float* __restrict__ Wih1,
                                                  const float* __restrict__ bih1,
                                                  const float* __restrict__ bhh1,
                                                  _Float16* __restrict__ G1x) {
  const int br = blockIdx.x >> 10;
  const int sp = blockIdx.x & 1023;
  const int s  = sp * 2 + (threadIdx.x >> 7);
  const int j  = threadIdx.x & 127;
  const float* px = xbn + br * 6144 + s * 3;
  const float x0 = px[0], x1 = px[1], x2 = px[2];
  _Float16* base =
      G1x + ((size_t)(br * 128 + (s >> 4)) * 512 + ridx0_of(j)) * 16 + (s & 15);
#pragma unroll
  for (int g = 0; g < 4; ++g) {
    const int row = g * 128 + j;
    float a = bih1[row] + bhh1[row] + Wih1[row * 3] * x0 +
              Wih1[row * 3 + 1] * x1 + Wih1[row * 3 + 2] * x2;
    a *= (g == 2) ? (2.0f * LOG2E) : LOG2E;
    base[g * 16] = (_Float16)a;
  }
}

// ---------------------------------------------------------------------------
// K3a: BN2 stats per (branch, channel) over 2048 elems of H1.
// ---------------------------------------------------------------------------
__global__ __launch_bounds__(256) void bn2stats_kernel(const float* __restrict__ H1,
                                                       float* __restrict__ stats) {
  const int br = blockIdx.x >> 7;
  const int ch = blockIdx.x & 127;
  const float* base = H1 + (size_t)br * 262144 + ch * 128;
  float s = 0.f, ss = 0.f;
  for (int k = threadIdx.x; k < 2048; k += 256) {
    const int t1 = k >> 7, h = k & 127;
    const float v = base[t1 * 16384 + h];
    s += v;
    ss += v * v;
  }
  for (int off = 32; off; off >>= 1) {
    s  += __shfl_down(s, off);
    ss += __shfl_down(ss, off);
  }
  __shared__ float red[8];
  if ((threadIdx.x & 63) == 0) {
    red[(threadIdx.x >> 6) * 2]     = s;
    red[(threadIdx.x >> 6) * 2 + 1] = ss;
  }
  __syncthreads();
  if (threadIdx.x == 0) {
    const float S  = red[0] + red[2] + red[4] + red[6];
    const float SS = red[1] + red[3] + red[5] + red[7];
    const float mean = S * (1.0f / 2048.0f);
    const float var  = SS * (1.0f / 2048.0f) - mean * mean;
    stats[(br * 128 + ch) * 2]     = mean;
    stats[(br * 128 + ch) * 2 + 1] = rsqrtf(var + 1e-5f);
  }
}

// ---------------------------------------------------------------------------
// K3b: G2x = (Wih2 @ BN2(H1) + biases) * log2e, chunked layout w/ ridx map.
// Gate 2 pre-doubled (see g1x).
// ---------------------------------------------------------------------------
__global__ __launch_bounds__(256) void g2x_kernel(
    const float* __restrict__ H1, const float* __restrict__ stats,
    const float* __restrict__ g2, const float* __restrict__ b2v,
    const float* __restrict__ Wih2, const float* __restrict__ bih2,
    const float* __restrict__ bhh2, _Float16* __restrict__ G2x) {
  const int br = blockIdx.x >> 7;
  const int t2 = blockIdx.x & 127;
  __shared__ float xh[2048];
  __shared__ float wt[64 * 129];
  const float mean = stats[(br * 128 + t2) * 2];
  const float rstd = stats[(br * 128 + t2) * 2 + 1];
  const float a  = g2[t2] * rstd;
  const float sh = b2v[t2] - mean * a;
  for (int e = threadIdx.x; e < 2048; e += 256) {
    const int b2 = e >> 7, d = e & 127;
    xh[e] = H1[(size_t)br * 262144 + (size_t)(b2 * 128 + t2) * 128 + d] * a + sh;
  }
  const int gl  = threadIdx.x & 63;
  const int b2b = (threadIdx.x >> 6) * 4;
  for (int gt = 0; gt < 8; ++gt) {
    __syncthreads();
    for (int e = threadIdx.x; e < 8192; e += 256)
      wt[(e >> 7) * 129 + (e & 127)] = Wih2[gt * 8192 + e];
    __syncthreads();
    float a0 = 0.f, a1 = 0.f, a2 = 0.f, a3 = 0.f;
    for (int d = 0; d < 128; ++d) {
      const float w = wt[gl * 129 + d];
      a0 += w * xh[(b2b + 0) * 128 + d];
      a1 += w * xh[(b2b + 1) * 128 + d];
      a2 += w * xh[(b2b + 2) * 128 + d];
      a3 += w * xh[(b2b + 3) * 128 + d];
    }
    const int g    = gt * 64 + gl;
    const int gate = g >> 7;
    const int jj   = g & 127;
    const int ri   = ridx0_of(jj) + gate;
    const float bb = bih2[g] + bhh2[g];
    const float mul = (gate == 2) ? (2.0f * LOG2E) : LOG2E;
    _Float16* dst = G2x + ((size_t)(br * 128 + t2) * 512 + ri) * 16 + b2b;
    *reinterpret_cast<half4_t*>(dst) =
        half4_t{(_Float16)((a0 + bb) * mul), (_Float16)((a1 + bb) * mul),
                (_Float16)((a2 + bb) * mul), (_Float16)((a3 + bb) * mul)};
  }
}

// ---------------------------------------------------------------------------
// K2/K4: the recurrence. 1 block/branch, 512 threads (8 waves, 2/SIMD).
// i8 MFMA 16x16x64: wave w owns one 16-row m-tile per gate; 8 MFMAs/wave/step.
// Cell state kept pre-scaled: cp = 2*log2e*c. Gate-2 lane's activation is
// folded to 2.885*tanh (B=5.7708, C=2.8854) so the broadcast gv' feeds the
// cp update AND the exp2-factorized tanh: e^{2c} = exp2(fv*cp)*exp2(iv*gv').
// Step 0 preact computed EXACTLY in f32 at init (overrides MFMA result).
// h quantized with error feedback (noise shaping, residual kept 127-scaled).
// One lgkm-only barrier per step. Gx: 2 half8 loads / 16-step chunk.
// ---------------------------------------------------------------------------
__global__ __launch_bounds__(512, 1) void lstm_kernel(
    const float* __restrict__ Whh, const float* __restrict__ h0s,
    const float* __restrict__ c0s, const _Float16* __restrict__ Gx,
    float* __restrict__ outp, int layer) {
  const int br   = blockIdx.x;
  const int tid  = threadIdx.x;
  const int wave = tid >> 6;
  const int lane = tid & 63;
  const int quad = lane >> 4;
  const int l15  = lane & 15;
  const int gate = l15 & 3;
  const int rr   = l15 >> 2;
  const int j    = wave * 16 + quad * 4 + rr;  // this lane's cell row
  const bool rb0 = (rr & 1) != 0;
  const bool rb1 = (rr & 2) != 0;
  const bool gb0 = (gate & 1) != 0;
  const bool gb1 = (gate & 2) != 0;
  // unified activation: sigm (i,f,o): act = 1 - rcp(1+exp2(a)).
  // tanh gate (g): act' = 2.8854*tanh = 2.8854 - 5.7708*rcp(1+exp2(a))
  // (input scale s=2 pre-folded into Gx/s_own/exact0; output scale 2*log2e
  // folded into B/C so the broadcast value directly feeds the cp update and
  // the exp2-factorized tanh).
  const float scg = (gate == 2) ? 2.0f : 1.0f;
  const float Bcg = (gate == 2) ? 5.77078016f : 1.0f;
  const float Ccg = (gate == 2) ? 2.88539008f : 1.0f;

  __shared__ __align__(16) signed char h_sh[2][128];
  __shared__ float rowscale[512];
  __shared__ __align__(16) float h0f[128];

  // ---- quantize Whh to i8 A-fragments (per-row scale), 4 gates x 2 k ----
  int4_t afrag[4][2];
#pragma unroll
  for (int g = 0; g < 4; ++g) {
    const int row = g * 128 + wave * 16 + l15;
    const float4_t* wr = (const float4_t*)(Whh + row * 128);
    float m = 1e-8f;
    for (int k4 = 0; k4 < 32; ++k4) {
      const float4_t v = wr[k4];
      m = fmaxf(m, fmaxf(fmaxf(fabsf(v[0]), fabsf(v[1])),
                         fmaxf(fabsf(v[2]), fabsf(v[3]))));
    }
    if (quad == 0) rowscale[row] = m;
    const float inv = 127.0f / m;
#pragma unroll
    for (int t = 0; t < 2; ++t) {
      int4_t f;
#pragma unroll
      for (int w = 0; w < 4; ++w) {
        int word = 0;
#pragma unroll
        for (int b = 0; b < 4; ++b) {
          const int k = t * 64 + quad * 16 + w * 4 + b;
          const int q = (int)__builtin_rintf(Whh[row * 128 + k] * inv);
          word |= (q & 255) << (8 * b);
        }
        f[w] = word;
      }
      afrag[g][t] = f;
    }
  }

  const int slot = 2 * br + layer;
  // pre-scaled cell state: cp = 2*log2e * c  (4 gate-lanes per j identical)
  float cp = c0s[slot * 128 + j] * 2.88539008f;
  if (tid < 128) {
    const float h0 = h0s[slot * 128 + tid];
    h0f[tid] = h0;
    // i8 encoding of h0 is irrelevant (step-0 MFMA result is overridden);
    // clip for sanity.
    float qf = __builtin_rintf(h0 * 127.0f);
    qf = fminf(fmaxf(qf, -127.0f), 127.0f);
    h_sh[0][tid] = (signed char)(int)qf;
  }

  // Gx chunk stream: record = 16 halfs at ((br*128+ch)*512 + tid)*16
  const half8* gq = (const half8*)Gx;
  half8 curA = gq[((size_t)(br * 128) * 512 + tid) * 2];
  half8 curB = gq[((size_t)(br * 128) * 512 + tid) * 2 + 1];
  float* const obase = outp + (size_t)br * 262144;

  const int4_t zi = {0, 0, 0, 0};
  __syncthreads();  // publishes rowscale + h0f

  // dequant scale for this lane's owned cell row (log2e + tanh-scale folded)
  const float s_own =
      rowscale[gate * 128 + j] * (LOG2E / (127.0f * 127.0f)) * scg;

  // ---- EXACT f32 step-0 preact for the owned cell (one-time) ----
  float exact0;
  {
    const int rowo = gate * 128 + j;
    const float4_t* wr4 = (const float4_t*)(Whh + rowo * 128);
    const float4_t* h04 = (const float4_t*)h0f;
    float e0 = 0.f, e1 = 0.f;
#pragma unroll 8
    for (int k4 = 0; k4 < 32; k4 += 2) {
      const float4_t a0 = wr4[k4],     b0 = h04[k4];
      const float4_t a1 = wr4[k4 + 1], b1 = h04[k4 + 1];
      e0 = __builtin_fmaf(a0[0], b0[0], e0);
      e0 = __builtin_fmaf(a0[1], b0[1], e0);
      e0 = __builtin_fmaf(a0[2], b0[2], e0);
      e0 = __builtin_fmaf(a0[3], b0[3], e0);
      e1 = __builtin_fmaf(a1[0], b1[0], e1);
      e1 = __builtin_fmaf(a1[1], b1[1], e1);
      e1 = __builtin_fmaf(a1[2], b1[2], e1);
      e1 = __builtin_fmaf(a1[3], b1[3], e1);
    }
    exact0 = (e0 + e1) * (LOG2E * scg);
  }

  // ---- phase stagger: one hi-prio wave per SIMD (measured neutral in R17
  // A/B but harmless; kept to match the verified-best binary structure).
  if (((wave ^ (wave >> 2)) & 1) != 0) __builtin_amdgcn_s_setprio(2);

  float qres = 0.f;  // noise-shaping residual, kept in 127-scale

  for (int chk = 0; chk < 128; ++chk) {
    const int chn = (chk < 127) ? chk + 1 : 127;
    const size_t nrec = ((size_t)(br * 128 + chn) * 512 + tid) * 2;
    const half8 nA = gq[nrec], nB = gq[nrec + 1];  // waited at chunk end

#pragma unroll
    for (int u = 0; u < 16; ++u) {
      // B fragments: 16 i8 per lane per k-half (same addr per quad -> bcast)
      const signed char* hs = h_sh[u & 1];
      const int4_t b0 = *(const int4_t*)(hs + quad * 16);
      const int4_t b1 = *(const int4_t*)(hs + 64 + quad * 16);

      const float pre = (float)((u < 8) ? curA[u] : curB[u - 8]);

      // 4 independent i8 MFMA chains (one per gate), depth 2
      int4_t acc[4];
#pragma unroll
      for (int g = 0; g < 4; ++g)
        acc[g] = __builtin_amdgcn_mfma_i32_16x16x64_i8(afrag[g][0], b0, zi, 0, 0, 0);
#pragma unroll
      for (int g = 0; g < 4; ++g)
        acc[g] = __builtin_amdgcn_mfma_i32_16x16x64_i8(afrag[g][1], b1, acc[g], 0, 0, 0);

      // int selects: element rr of each gate's acc, then own gate
      int e0, e1, e2, e3;
      {
        int x, y;
        x = rb0 ? acc[0][1] : acc[0][0]; y = rb0 ? acc[0][3] : acc[0][2];
        e0 = rb1 ? y : x;
        x = rb0 ? acc[1][1] : acc[1][0]; y = rb0 ? acc[1][3] : acc[1][2];
        e1 = rb1 ? y : x;
        x = rb0 ? acc[2][1] : acc[2][0]; y = rb0 ? acc[2][3] : acc[2][2];
        e2 = rb1 ? y : x;
        x = rb0 ? acc[3][1] : acc[3][0]; y = rb0 ? acc[3][3] : acc[3][2];
        e3 = rb1 ? y : x;
      }
      const int eA = gb0 ? e1 : e0;
      const int eB = gb0 ? e3 : e2;
      const int ei = gb1 ? eB : eA;

      float a = __builtin_fmaf((float)ei, s_own, pre);
      if (u == 0 && chk == 0) a = exact0 + pre;  // exact step 0 (no h0 quant)

      // unified activation (tanh lanes output 2.8854*tanh via B/C folding)
      const float act = __builtin_fmaf(-Bcg, fast_rcp(1.0f + exp2b(a)), Ccg);

      // collect the 4 gates across the aligned 4-lane group
      const float iv = QBCAST(act, 0x00);
      const float fv = QBCAST(act, 0x55);
      const float gv = QBCAST(act, 0xAA);  // = 2.8854 * g
      const float ov = QBCAST(act, 0xFF);

      // exp2-factorized tanh: e^{2c_new} = exp2(m1) * exp2(m2); both trans
      // ops start right after their mul and run in parallel.
      const float m1 = fv * cp;
      const float m2 = iv * gv;
      cp = m1 + m2;  // = 2.8854 * c_new (off the critical path)
      const float ep = exp2b(m1) * exp2b(m2);
      const float t  = __builtin_fmaf(-2.0f, fast_rcp(1.0f + ep), 1.0f);
      const float hv = ov * t;

      if (gate == 0) {
        // noise-shaped quantization, residual kept 127-scaled:
        //   t2 = 127*hv + qres; qf = clamp(rint(t2)); qres' = t2 - qf
        const float t2 = __builtin_fmaf(hv, 127.0f, qres);
        float qf = __builtin_rintf(t2);
        qf = __builtin_amdgcn_fmed3f(qf, -127.0f, 127.0f);
        qres = t2 - qf;
        h_sh[(u + 1) & 1][j] = (signed char)(int)qf;
        // uniform row pointer: step advance is scalar (saddr form)
        float* orow = obase + (size_t)(chk * 16 + u) * 128;
        orow[j] = hv;  // output keeps full precision
      }
      lds_barrier();  // h broadcast; lgkm-only
    }

    curA = nA;  // vmcnt wait lands here, one full chunk after issue
    curB = nB;
  }
}

// ---------------------------------------------------------------------------
// Workspace layout (floats):
//   xbn   [3][2048][3]            @ 0        (18432)
//   H1    [3][2048][128]          @ 18432    (786432)
//   stats [3][128][2]             @ 804864   (768)
//   G1x   chunked f16             @ 805632   (1572864 floats)
//   G2x   chunked f16             @ 2378496  (1572864 floats)   total ~15.8 MB
// ---------------------------------------------------------------------------
extern "C" void kernel_launch(void* const* d_in, const int* in_sizes, int n_in,
                              void* d_out, int out_size, void* d_ws, size_t ws_size,
                              hipStream_t stream) {
  const float* x    = (const float*)d_in[0];
  const float* g1   = (const float*)d_in[1];
  const float* b1   = (const float*)d_in[2];
  const float* Wih1 = (const float*)d_in[3];
  const float* Whh1 = (const float*)d_in[4];
  const float* bih1 = (const float*)d_in[5];
  const float* bhh1 = (const float*)d_in[6];
  const float* g2   = (const float*)d_in[7];
  const float* b2   = (const float*)d_in[8];
  const float* Wih2 = (const float*)d_in[9];
  const float* Whh2 = (const float*)d_in[10];
  const float* bih2 = (const float*)d_in[11];
  const float* bhh2 = (const float*)d_in[12];
  const float* h0s  = (const float*)d_in[13];
  const float* c0s  = (const float*)d_in[14];

  float* ws   = (float*)d_ws;
  float* xbn  = ws;
  float* H1b  = ws + 18432;
  float* st   = ws + 18432 + 786432;
  _Float16* G1xb = (_Float16*)(ws + 805632);
  _Float16* G2xb = (_Float16*)(ws + 2378496);
  float* outp = (float*)d_out;

  bn1_kernel<<<48, 128, 0, stream>>>(x, g1, b1, xbn);
  g1x_kernel<<<3072, 256, 0, stream>>>(xbn, Wih1, bih1, bhh1, G1xb);
  lstm_kernel<<<3, 512, 0, stream>>>(Whh1, h0s, c0s, G1xb, H1b, 0);
  bn2stats_kernel<<<384, 256, 0, stream>>>(H1b, st);
  g2x_kernel<<<384, 256, 0, stream>>>(H1b, st, g2, b2, Wih2, bih2, bhh2, G2xb);
  lstm_kernel<<<3, 512, 0, stream>>>(Whh2, h0s, c0s, G2xb, outp, 1);
}